// Round 7
// baseline (40.914 us; speedup 1.0000x reference)
//
#include <hip/hip_runtime.h>

#define N_    2
#define C_    128
#define H_    128
#define W_    128
#define COUT_ 128
#define K_    9
#define HO_   128
#define WO_   128
#define HW_   (H_*W_)

typedef __attribute__((ext_vector_type(8))) short  short8v;
typedef __attribute__((ext_vector_type(4))) float  float4v;
typedef __attribute__((ext_vector_type(2))) float  float2v;
typedef __attribute__((ext_vector_type(4))) unsigned int uint4v;

__device__ __forceinline__ unsigned short f2bf(float f) {
    union { float f; unsigned int u; } v; v.f = f;
    return (unsigned short)((v.u + 0x7FFFu + ((v.u >> 16) & 1u)) >> 16);  // RNE
}
__device__ __forceinline__ float bflo(unsigned int u) {
    union { unsigned int u; float f; } v; v.u = u << 16; return v.f;
}
__device__ __forceinline__ float bfhi(unsigned int u) {
    union { unsigned int u; float f; } v; v.u = u & 0xFFFF0000u; return v.f;
}
__device__ __forceinline__ unsigned int cvt_pk_bf16(float lo, float hi) {
    unsigned int r;
    asm("v_cvt_pk_bf16_f32 %0, %1, %2" : "=v"(r) : "v"(lo), "v"(hi));  // RNE pack
    return r;
}

// ---- one-time prep: weight pack (A-fragment order) + CHW->HWC bf16 --------
__global__ __launch_bounds__(256)
void prep(const float* __restrict__ x, const float* __restrict__ w,
          unsigned short* __restrict__ xT, unsigned short* __restrict__ wb) {
    if (blockIdx.x >= 256) {                       // ---- pack_w part
        const int t = (blockIdx.x - 256) * 256 + threadIdx.x;
        if (t >= 9 * 8 * 4 * 64) return;
        const int l  = t & 63;
        const int ks = (t >> 6) & 3;
        const int mt = (t >> 8) & 7;
        const int kk = t >> 11;
        const int row = mt * 16 + (l & 15);
        const int c0  = ks * 32 + (l >> 4) * 8;
        unsigned short pk[8];
        #pragma unroll
        for (int j = 0; j < 8; ++j)
            pk[j] = f2bf(w[row * (C_ * K_) + (c0 + j) * K_ + kk]);
        *((short8v*)wb + t) = *(short8v*)pk;
        return;
    }
    // ---- xpose part: one n (bid>>7), 128 pixels
    __shared__ unsigned short tile[128][136];
    const int t  = threadIdx.x;
    const int n  = blockIdx.x >> 7;
    const int p0 = (blockIdx.x & 127) * 128;
    #pragma unroll 4
    for (int i = 0; i < 32; ++i) {
        const int q = i * 2 + (t >> 7);
        const int p = t & 127;
        const float v0 = x[((size_t)(n * C_ + 2 * q    )) * HW_ + p0 + p];
        const float v1 = x[((size_t)(n * C_ + 2 * q + 1)) * HW_ + p0 + p];
        const unsigned int u = (unsigned int)f2bf(v0) | ((unsigned int)f2bf(v1) << 16);
        *(unsigned int*)&tile[p][2 * q] = u;
    }
    __syncthreads();
    const int p    = t >> 1;
    const int half = t & 1;
    unsigned short* dst = xT + ((size_t)(n * HW_ + p0 + p) << 7) + half * 64;
    #pragma unroll
    for (int j = 0; j < 8; ++j)
        *(short8v*)(dst + j * 8) = *(short8v*)&tile[p][half * 64 + j * 8];
}

// ---- fused deformable-im2col + MFMA GEMM -----------------------------------
// 1024 blocks x 256 threads (32-px tiles) -> 4 independent blocks/CU for
// cross-block phase overlap. Wave = 32 cout x 32 px. Single non-draining
// barrier per tap; gather prefetched 1 tap ahead; A prefetched per tap.
__global__ __launch_bounds__(256, 4)
void dcn_mfma(const unsigned short* __restrict__ xT,
              const float* __restrict__ offset,
              const float* __restrict__ mask,
              const unsigned short* __restrict__ wbuf,
              const float* __restrict__ bias,
              float* __restrict__ out)
{
    __shared__ unsigned short colsT[2][32 * 128]; // 16 KB double-buffered
    __shared__ int4   samp_a[K_ * 32];            // 4.6 KB
    __shared__ float4 samp_w[K_ * 32];            // 4.6 KB

    const int tid = threadIdx.x;
    const int lid = (blockIdx.x & 7) * 128 + (blockIdx.x >> 3);  // XCD swizzle
    const int n   = lid >> 9;
    const int ho  = (lid >> 2) & 127;
    const int wo0 = (lid & 3) * 32;

    // ---- metadata for all 9 taps x 32 pixels ------------------------------
    for (int e = tid; e < K_ * 32; e += 256) {
        const int kk  = e >> 5;
        const int wol = e & 31;
        const int wo  = wo0 + wol;
        const int iy = kk / 3, ix = kk % 3;
        const int ob = ((n * 2 * K_ + 2 * kk) * HO_ + ho) * WO_ + wo;
        const float offy = offset[ob];
        const float offx = offset[ob + HO_ * WO_];
        const float m    = mask[((n * K_ + kk) * HO_ + ho) * WO_ + wo];
        const float ys = (float)(ho - 1 + iy) + offy;
        const float xs = (float)(wo - 1 + ix) + offx;
        const float y0f = floorf(ys), x0f = floorf(xs);
        const float ly = ys - y0f, lx = xs - x0f;
        const int y0 = (int)y0f, x0 = (int)x0f;
        const int y1 = y0 + 1,  x1 = x0 + 1;
        const float vy0 = (y0 >= 0 && y0 < H_) ? 1.f : 0.f;
        const float vy1 = (y1 >= 0 && y1 < H_) ? 1.f : 0.f;
        const float vx0 = (x0 >= 0 && x0 < W_) ? 1.f : 0.f;
        const float vx1 = (x1 >= 0 && x1 < W_) ? 1.f : 0.f;
        const int y0c = min(max(y0, 0), H_-1), y1c = min(max(y1, 0), H_-1);
        const int x0c = min(max(x0, 0), W_-1), x1c = min(max(x1, 0), W_-1);
        samp_a[e] = make_int4(y0c*W_+x0c, y0c*W_+x1c, y1c*W_+x0c, y1c*W_+x1c);
        samp_w[e] = make_float4((1.f-ly)*(1.f-lx)*m*vy0*vx0,
                                (1.f-ly)*lx      *m*vy0*vx1,
                                ly      *(1.f-lx)*m*vy1*vx0,
                                ly      *lx      *m*vy1*vx1);
    }
    __syncthreads();

    const int lane = tid & 63;
    const int wv   = tid >> 6;          // wave 0..3
    const int p    = tid >> 3;          // pixel 0..31
    const int s    = tid & 7;           // 16-channel chunk
    const int so   = s * 32;
    const int mt0  = wv * 2;            // wave's 2 cout-tiles of 16
    float4v acc[2][2] = {};             // 32 cout x 32 px per wave

    const char* xb = (const char*)xT + ((size_t)n * HW_) * 256;
    const short8v* wb = (const short8v*)wbuf;

    // ---- prologue: issue tap-0 gathers ------------------------------------
    uint4v ga[4][2];
    float4 w4;
    {
        const int4 a0 = samp_a[p];
        w4 = samp_w[p];
        const char* b0 = xb + (size_t)a0.x * 256 + so;
        const char* b1 = xb + (size_t)a0.y * 256 + so;
        const char* b2 = xb + (size_t)a0.z * 256 + so;
        const char* b3 = xb + (size_t)a0.w * 256 + so;
        ga[0][0] = *(const uint4v*)b0;  ga[0][1] = *(const uint4v*)(b0 + 16);
        ga[1][0] = *(const uint4v*)b1;  ga[1][1] = *(const uint4v*)(b1 + 16);
        ga[2][0] = *(const uint4v*)b2;  ga[2][1] = *(const uint4v*)(b2 + 16);
        ga[3][0] = *(const uint4v*)b3;  ga[3][1] = *(const uint4v*)(b3 + 16);
    }

    #pragma unroll
    for (int kk = 0; kk < K_; ++kk) {
        const int cur = kk & 1;

        // ---- issue this tap's A-fragments (land during combine) -----------
        short8v af[2][4];
        #pragma unroll
        for (int ks = 0; ks < 4; ++ks) {
            af[0][ks] = wb[((kk * 8 + mt0    ) * 4 + ks) * 64 + lane];
            af[1][ks] = wb[((kk * 8 + mt0 + 1) * 4 + ks) * 64 + lane];
        }

        // ---- packed bilinear combine + cvt_pk pack ------------------------
        const float2v wx = {w4.x, w4.x};
        const float2v wy = {w4.y, w4.y};
        const float2v wz = {w4.z, w4.z};
        const float2v ww = {w4.w, w4.w};
        uint4v res[2];
        #pragma unroll
        for (int h = 0; h < 2; ++h)
            #pragma unroll
            for (int j = 0; j < 4; ++j) {
                const unsigned int u00 = ga[0][h][j], u01 = ga[1][h][j];
                const unsigned int u10 = ga[2][h][j], u11 = ga[3][h][j];
                const float2v f00 = {bflo(u00), bfhi(u00)};
                const float2v f01 = {bflo(u01), bfhi(u01)};
                const float2v f10 = {bflo(u10), bfhi(u10)};
                const float2v f11 = {bflo(u11), bfhi(u11)};
                const float2v v = wx*f00 + wy*f01 + wz*f10 + ww*f11;
                res[h][j] = cvt_pk_bf16(v[0], v[1]);
            }

        // ---- prefetch tap kk+1 gathers (land during barrier+MFMA) ---------
        if (kk < K_ - 1) {
            const int4 a1 = samp_a[(kk + 1) * 32 + p];
            w4 = samp_w[(kk + 1) * 32 + p];
            const char* b0 = xb + (size_t)a1.x * 256 + so;
            const char* b1 = xb + (size_t)a1.y * 256 + so;
            const char* b2 = xb + (size_t)a1.z * 256 + so;
            const char* b3 = xb + (size_t)a1.w * 256 + so;
            ga[0][0] = *(const uint4v*)b0;  ga[0][1] = *(const uint4v*)(b0 + 16);
            ga[1][0] = *(const uint4v*)b1;  ga[1][1] = *(const uint4v*)(b1 + 16);
            ga[2][0] = *(const uint4v*)b2;  ga[2][1] = *(const uint4v*)(b2 + 16);
            ga[3][0] = *(const uint4v*)b3;  ga[3][1] = *(const uint4v*)(b3 + 16);
        }

        // ---- publish into LDS buffer `cur` --------------------------------
        {
            char* cb = (char*)colsT[cur];
            const int base = p * 256 + so;
            const int swz  = (p & 7) << 4;
            *(uint4v*)(cb + ((base     ) ^ swz)) = res[0];
            *(uint4v*)(cb + ((base + 16) ^ swz)) = res[1];
        }

        // ---- non-draining barrier: LDS drained, VMEM stays in flight ------
        asm volatile("s_waitcnt lgkmcnt(0)" ::: "memory");
        __builtin_amdgcn_s_barrier();

        // ---- MFMA: 4 k-steps x 2 n-tiles x 2 m-tiles ----------------------
        #pragma unroll
        for (int ks = 0; ks < 4; ++ks) {
            short8v b[2];
            #pragma unroll
            for (int nt = 0; nt < 2; ++nt) {
                const int row = nt * 16 + (lane & 15);
                const int byte = (row * 256 + ks * 64 + (lane >> 4) * 16)
                               ^ ((row & 7) << 4);
                b[nt] = *(const short8v*)((const char*)colsT[cur] + byte);
            }
            #pragma unroll
            for (int nt = 0; nt < 2; ++nt) {
                acc[0][nt] = __builtin_amdgcn_mfma_f32_16x16x32_bf16(af[0][ks], b[nt], acc[0][nt], 0, 0, 0);
                acc[1][nt] = __builtin_amdgcn_mfma_f32_16x16x32_bf16(af[1][ks], b[nt], acc[1][nt], 0, 0, 0);
            }
        }
    }

    // ---- epilogue: D layout col=lane&15 (wo), row=(lane>>4)*4+reg (cout) --
    const int colw  = lane & 15;
    const int rquad = (lane >> 4) * 4;
    #pragma unroll
    for (int mi = 0; mi < 2; ++mi) {
        #pragma unroll
        for (int nt = 0; nt < 2; ++nt) {
            const int woe = wo0 + nt * 16 + colw;
            #pragma unroll
            for (int r = 0; r < 4; ++r) {
                const int co = (mt0 + mi) * 16 + rquad + r;
                out[((size_t)(n * COUT_ + co) * HO_ + ho) * WO_ + woe] = acc[mi][nt][r] + bias[co];
            }
        }
    }
}

extern "C" void kernel_launch(void* const* d_in, const int* in_sizes, int n_in,
                              void* d_out, int out_size, void* d_ws, size_t ws_size,
                              hipStream_t stream) {
    const float* x      = (const float*)d_in[0];
    const float* offset = (const float*)d_in[1];
    const float* mask   = (const float*)d_in[2];
    const float* weight = (const float*)d_in[3];
    const float* bias   = (const float*)d_in[4];
    float* out = (float*)d_out;

    unsigned short* xT   = (unsigned short*)d_ws;                    // 8,388,608 B
    unsigned short* wbuf = (unsigned short*)((char*)d_ws + 8388608); // +294,912 B

    prep<<<328, 256, 0, stream>>>(x, weight, xT, wbuf);
    dcn_mfma<<<N_ * HO_ * 4, 256, 0, stream>>>(xT, offset, mask, wbuf, bias, out);
}